// Round 9
// baseline (1134.949 us; speedup 1.0000x reference)
//
#include <hip/hip_runtime.h>
#include <math.h>
#include <stdint.h>

// SLAYER 2-layer SNN. Round 9: fully-fused layers + exact i8-MFMA digit planes.
//   bitifyT -> decompose_i8(W -> 5 int8 digit planes) -> memset(bitsH) ->
//   snn_layer_fused<1024>(bits1 -> bitsH via atomicOr) ->
//   snn_layer_fused<2048>(bitsH -> f32 out).
// Per block (b, 16 o): [i8 MFMA gemm over all 256 t] -> fp64 a in LDS ->
// [chunked 61-tap conv (waves 1-3) pipelined with sequential scan (wave 0)]
// -> spike ballots out. a/u never touch HBM.
// Exactness: w = (sum_p d_p 256^p)*2^-38, d_p int8; i8xi8->i32 MFMA exact
// (sums < 2^18); fp64 recombine exact -> a bit-identical to R8 (absmax 0.0).
// conv inner loop and scan arithmetic ported verbatim from R8.

#define TT     256
#define KLEN   62
#define THETA  10.0

typedef int v4i __attribute__((ext_vector_type(4)));

// ============================ bitify (transposed) ===========================
// x: [32][1024][256] f32 {0,1}; bitsT: [b][32 words][256 t]
__global__ __launch_bounds__(256)
void bitifyT(const float* __restrict__ x, uint32_t* __restrict__ bitsT)
{
    const int b  = blockIdx.x;
    const int ig = blockIdx.y;            // group of 128 inputs (4 words)
    const int t  = threadIdx.x;
    const float* xp = x     + ((size_t)b*1024 + ig*128)*TT + t;
    uint32_t*    bp = bitsT + ((size_t)b*32 + ig*4)*TT + t;
    for (int wi = 0; wi < 4; ++wi) {
        uint32_t wb = 0;
        #pragma unroll
        for (int j = 0; j < 32; ++j)
            wb |= (xp[(size_t)(wi*32 + j)*TT] >= 0.5f) ? (1u << j) : 0u;
        bp[(size_t)wi * TT] = wb;
    }
}

// ====================== weight -> int8 digit-plane decompose ================
// planes: [oblk][ks(I/64)][mp(80 = p*16+mo)][80 bytes (64 k + 16 pad)]
__global__ __launch_bounds__(256)
void decompose_i8(const float* __restrict__ w, signed char* __restrict__ planes,
                  int I, int total)
{
    const int f = blockIdx.x * 256 + threadIdx.x;
    if (f >= total) return;
    const int NS = I / 64;
    const int per_oblk = NS * 6400;
    int rem  = f;
    const int oblk = rem / per_oblk;  rem -= oblk * per_oblk;
    const int ks   = rem / 6400;      rem -= ks * 6400;
    const int mp   = rem / 80;
    const int kk   = rem - mp * 80;
    signed char h = 0;
    if (kk < 64) {
        const int p  = mp >> 4, mo = mp & 15;
        const float wv = w[(size_t)(oblk*16 + mo) * I + ks*64 + kk];
        long long v = llrint((double)wv * 274877906944.0);   // w * 2^38, exact int
        int d = 0;
        for (int q = 0; q <= p; ++q) {                       // balanced base-256
            d = (int)((v + 128) & 255) - 128;
            v = (v - d) >> 8;
        }
        h = (signed char)d;
    }
    planes[f] = h;
}

// ====================== fused layer kernel ==================================
// grid (O/16, B), block 256. FINAL=false: spikes -> bitsT_out via atomicOr
// (pre-zeroed); FINAL=true: spikes -> f32 out[b][o][t].
template<int I, bool FINAL>
__global__ __launch_bounds__(256)
void snn_layer_fused(const uint32_t*    __restrict__ bitsT,     // [B][I/32][256]
                     const signed char* __restrict__ planes,
                     uint32_t*          __restrict__ bitsT_out, // [B][64][256]
                     float*             __restrict__ f32_out)   // [B][512][256]
{
    constexpr int IW = I / 32;
    constexpr int NS = I / 64;
    __shared__ __align__(16) signed char ash[2][6400];   // 12.8 KB A dbuf
    __shared__ double a_lds[257 * 17];                   // 34.95 KB (row 256 = zeros)
    __shared__ double u_lds[2][32 * 17];                 // 8.7 KB
    __shared__ double srmE[68];
    __shared__ double ref64[KLEN];
    __shared__ ushort sp16[256];

    const int tid  = threadIdx.x;
    const int lane = tid & 63;
    const int wvu  = tid >> 6;
    const int quad = lane >> 4;
    const int col  = lane & 15;
    const int b    = blockIdx.y;
    const int oblk = blockIdx.x;
    const int o0   = oblk * 16;
    const int tw   = wvu * 64;

    // fp32-rounded alpha-kernel taps, widened to f64 (identical to R1-R8)
    if (tid < 68) {
        const int k = tid - 2;
        double v = 0.0;
        if (k >= 1 && k <= 61) {
            double wv = (double)k / 8.0 * exp(1.0 - (double)k / 8.0);
            v = (double)(float)wv;
        }
        srmE[tid] = v;
    }
    if (tid < KLEN) {
        double v = (double)tid / 8.0 * exp(1.0 - (double)tid / 8.0);
        ref64[tid] = (double)(float)(-20.0 * v);
    }

    // ---------------- gemm phase: 5 i8 digit planes, K=64 -------------------
    const signed char* Apg = planes + (size_t)oblk * NS * 6400;
    const uint32_t*    bw  = bitsT + (size_t)b * IW * 256 + tw + col;

    v4i acc[5][4];
    #pragma unroll
    for (int p = 0; p < 5; ++p)
        #pragma unroll
        for (int nt = 0; nt < 4; ++nt)
            acc[p][nt] = (v4i){0, 0, 0, 0};

    uint4 st0, st1;
    auto ldglob = [&](int s) {                           // 400 uint4 per tile
        const uint4* src = (const uint4*)(Apg + (size_t)s * 6400);
        st0 = src[tid];
        if (tid < 144) st1 = src[256 + tid];
    };
    auto stw = [&](int s) {                              // linear, conflict-free
        uint4* dst = (uint4*)ash[s & 1];
        dst[tid] = st0;
        if (tid < 144) dst[256 + tid] = st1;
    };

    ldglob(0); stw(0);
    __syncthreads();

    for (int s = 0; s < NS; ++s) {
        const bool more = (s + 1 < NS);
        if (more) ldglob(s + 1);

        uint32_t m0[4], m1[4];
        #pragma unroll
        for (int nt = 0; nt < 4; ++nt) {
            m0[nt] = bw[(size_t)(2*s)     * 256 + nt * 16];
            m1[nt] = bw[(size_t)(2*s + 1) * 256 + nt * 16];
        }

        const signed char* ap = ash[s & 1];
        v4i af[5];
        #pragma unroll
        for (int p = 0; p < 5; ++p)
            af[p] = *(const v4i*)(const void*)(ap + (p*16 + col)*80 + quad*16);

        #pragma unroll
        for (int nt = 0; nt < 4; ++nt) {
            const uint32_t sel = (quad & 2) ? m1[nt] : m0[nt];
            const uint32_t h   = (sel >> ((quad & 1) * 16)) & 0xFFFFu;
            union { uint32_t u[4]; v4i v; } bf;
            #pragma unroll
            for (int j = 0; j < 4; ++j) {
                const uint32_t n = (h >> (4*j)) & 0xFu;
                bf.u[j] = (n * 0x00204081u) & 0x01010101u;   // 4 bits -> 4 i8 {0,1}
            }
            #pragma unroll
            for (int p = 0; p < 5; ++p)
                acc[p][nt] = __builtin_amdgcn_mfma_i32_16x16x64_i8(
                                 af[p], bf.v, acc[p][nt], 0, 0, 0);
        }

        if (more) stw(s + 1);
        __syncthreads();
    }

    // ---------------- recombine: exact fp64 a into LDS ----------------------
    // D[m=quad*4+r][n=col]: o = quad*4+r, t = tw + nt*16 + col.
    const double inv = 1.0 / 274877906944.0;             // 2^-38
    #pragma unroll
    for (int nt = 0; nt < 4; ++nt) {
        const int t = tw + nt*16 + col;
        #pragma unroll
        for (int r = 0; r < 4; ++r) {
            double v =            (double)acc[4][nt][r];
            v = v * 256.0 + (double)acc[3][nt][r];
            v = v * 256.0 + (double)acc[2][nt][r];
            v = v * 256.0 + (double)acc[1][nt][r];
            v = v * 256.0 + (double)acc[0][nt][r];
            a_lds[t * 17 + quad*4 + r] = v * inv;
        }
    }
    if (tid < 17) a_lds[256 * 17 + tid] = 0.0;           // zero-guard row

    // ---------------- conv (R8 inner loop) + scan, chunk-pipelined ----------
    // chunk = 32 t. conv unit = 4t x 1o (128 units). scan: wave0, lanes 0-15.
    auto conv_chunk = [&](int c, int widx) {
        if (widx >= 128) return;
        const int o   = widx & 15;
        const int tb  = (widx >> 4) * 4;
        const int T0b = c * 32 + tb;
        double u0 = 0, u1 = 0, u2 = 0, u3 = 0;
        double w1 = srmE[64], w2 = srmE[65], w3 = srmE[66];   // zero pads
        for (int d = 0; d < 64; d += 4) {
            const int row = T0b - 61 + d;
            const int r0 = (row + 0 < 0) ? 256 : row + 0;
            const int r1 = (row + 1 < 0) ? 256 : row + 1;
            const int r2 = (row + 2 < 0) ? 256 : row + 2;
            const int r3 = (row + 3 < 0) ? 256 : row + 3;
            const double av0 = a_lds[r0 * 17 + o];
            const double av1 = a_lds[r1 * 17 + o];
            const double av2 = a_lds[r2 * 17 + o];
            const double av3 = a_lds[r3 * 17 + o];
            const double n0 = srmE[63 - d], n1 = srmE[62 - d];
            const double n2 = srmE[61 - d], n3 = srmE[60 - d];
            u0 = fma(n0, av0, u0); u1 = fma(w1, av0, u1); u2 = fma(w2, av0, u2); u3 = fma(w3, av0, u3);
            u0 = fma(n1, av1, u0); u1 = fma(n0, av1, u1); u2 = fma(w1, av1, u2); u3 = fma(w2, av1, u3);
            u0 = fma(n2, av2, u0); u1 = fma(n1, av2, u1); u2 = fma(n0, av2, u2); u3 = fma(w1, av2, u3);
            u0 = fma(n3, av3, u0); u1 = fma(n2, av3, u1); u2 = fma(n1, av3, u2); u3 = fma(n0, av3, u3);
            w1 = n3; w2 = n2; w3 = n1;
        }
        double* up = &u_lds[c & 1][0];
        up[(tb + 0) * 17 + o] = u0;
        up[(tb + 1) * 17 + o] = u1;
        up[(tb + 2) * 17 + o] = u2;
        up[(tb + 3) * 17 + o] = u3;
    };

    uint64_t mask = 0;
    auto scan_chunk = [&](int c) {
        const int t0 = c * 32;
        const double* up = &u_lds[c & 1][0];
        for (int tl = 0; tl < 32; ++tl) {
            const double uv = (lane < 16) ? up[tl * 17 + lane] : -1.0e300;
            uint64_t m = mask;
            double r0 = 0.0, r1 = 0.0;
            while (m) {
                int p = __builtin_ctzll(m); m &= m - 1;
                r0 += ref64[p + 1];
                if (m) { int pq = __builtin_ctzll(m); m &= m - 1; r1 += ref64[pq + 1]; }
            }
            const bool s = (uv + (r0 + r1)) >= THETA;
            const uint64_t bal = __ballot(s);
            if (lane == 0) sp16[t0 + tl] = (ushort)(bal & 0xFFFFu);
            mask = ((mask << 1) | (s ? 1ull : 0ull)) & ((1ull << 61) - 1ull);
        }
    };

    __syncthreads();                   // a_lds + zero row visible
    conv_chunk(0, tid);                // all waves build u[0]
    for (int c = 0; c < 8; ++c) {
        __syncthreads();               // u[c] ready; u[(c+1)&1] free
        if (wvu == 0)      scan_chunk(c);
        else if (c + 1 < 8) conv_chunk(c + 1, tid - 64);
    }
    __syncthreads();

    // ---------------- spike output ------------------------------------------
    if (!FINAL) {
        // bit o0+j of word (o0>>5) at [b][word][t]; two blocks share a word
        const int t = tid;
        const uint32_t v = ((uint32_t)sp16[t]) << ((oblk & 1) * 16);
        atomicOr(bitsT_out + ((size_t)b * 64 + (o0 >> 5)) * 256 + t, v);
    } else {
        #pragma unroll
        for (int e = 0; e < 16; ++e) {
            const int ol = e, t = tid;
            f32_out[((size_t)b * 512 + o0 + ol) * 256 + t] =
                (float)((sp16[t] >> ol) & 1);
        }
    }
}

// ================================ launcher ==================================
extern "C" void kernel_launch(void* const* d_in, const int* in_sizes, int n_in,
                              void* d_out, int out_size, void* d_ws, size_t ws_size,
                              hipStream_t stream)
{
    const float* x  = (const float*)d_in[0];   // [32][1024][256]
    const float* w1 = (const float*)d_in[1];   // [2048][1024]
    const float* w2 = (const float*)d_in[2];   // [512][2048]
    float* out = (float*)d_out;                // [32][512][256]

    char* ws = (char*)d_ws;
    uint32_t* bits1 = (uint32_t*)ws;                       // 32*32*256*4 = 1 MB
    uint32_t* bitsH = (uint32_t*)(ws + (size_t)1048576);   // 32*64*256*4 = 2 MB
    size_t off = 1048576 + 2097152;
    signed char* P1 = (signed char*)(ws + off);            // 128*16*6400 = 13.1 MB
    off += (size_t)128 * 16 * 6400;
    signed char* P2 = (signed char*)(ws + off);            // 32*32*6400  = 6.55 MB

    bitifyT<<<dim3(32, 8), 256, 0, stream>>>(x, bits1);
    decompose_i8<<<dim3((13107200 + 255)/256), 256, 0, stream>>>(w1, P1, 1024, 13107200);
    decompose_i8<<<dim3((6553600  + 255)/256), 256, 0, stream>>>(w2, P2, 2048, 6553600);
    hipMemsetAsync(bitsH, 0, (size_t)2097152, stream);     // atomicOr target

    // layer 1: 1024 -> 2048 (spike bits out)
    snn_layer_fused<1024, false><<<dim3(128, 32), 256, 0, stream>>>(
        bits1, P1, bitsH, nullptr);
    // layer 2: 2048 -> 512 (f32 out)
    snn_layer_fused<2048, true><<<dim3(32, 32), 256, 0, stream>>>(
        bitsH, P2, nullptr, out);
}

// Round 10
// 716.034 us; speedup vs baseline: 1.5851x; 1.5851x over previous
//
#include <hip/hip_runtime.h>
#include <math.h>
#include <stdint.h>

// SLAYER 2-layer SNN. Round 10: fused gemm+conv (a in LDS), standalone scan.
//   bitifyT -> decompose_i8 x2 ->
//   fused_gc<1024> (bits1 -> u) -> scan<BITS> (u -> bitsH) ->
//   fused_gc<2048> (bitsH -> u) -> scan<F32>  (u -> f32 out).
// Verified pieces: i8 16x16x64 MFMA layout + bit-spread B-build + conv-from-LDS
// (R9, absmax 0.0); standalone scan (R8, absmax 0.0). R9's regression was the
// per-block serial scan; here scan is again TLP-parallel (lane = neuron).
// Exactness: w = (sum_p d_p 256^p)*2^-38 (d_p int8), i32 MFMA accum exact,
// fp64 recombine/conv/scan with fp32-rounded taps — identical arithmetic.

#define TT     256
#define KLEN   62
#define THETA  10.0

typedef int v4i __attribute__((ext_vector_type(4)));

// ============================ bitify (transposed) ===========================
// x: [32][1024][256] f32 {0,1}; bitsT: [b][32 words][256 t]
__global__ __launch_bounds__(256)
void bitifyT(const float* __restrict__ x, uint32_t* __restrict__ bitsT)
{
    const int b  = blockIdx.x;
    const int ig = blockIdx.y;            // group of 128 inputs (4 words)
    const int t  = threadIdx.x;
    const float* xp = x     + ((size_t)b*1024 + ig*128)*TT + t;
    uint32_t*    bp = bitsT + ((size_t)b*32 + ig*4)*TT + t;
    for (int wi = 0; wi < 4; ++wi) {
        uint32_t wb = 0;
        #pragma unroll
        for (int j = 0; j < 32; ++j)
            wb |= (xp[(size_t)(wi*32 + j)*TT] >= 0.5f) ? (1u << j) : 0u;
        bp[(size_t)wi * TT] = wb;
    }
}

// ====================== weight -> int8 digit-plane decompose ================
// planes: [oblk][ks(I/64)][mp(80 = p*16+mo)][80 bytes (64 k + 16 pad)]
__global__ __launch_bounds__(256)
void decompose_i8(const float* __restrict__ w, signed char* __restrict__ planes,
                  int I, int total)
{
    const int f = blockIdx.x * 256 + threadIdx.x;
    if (f >= total) return;
    const int NS = I / 64;
    const int per_oblk = NS * 6400;
    int rem  = f;
    const int oblk = rem / per_oblk;  rem -= oblk * per_oblk;
    const int ks   = rem / 6400;      rem -= ks * 6400;
    const int mp   = rem / 80;
    const int kk   = rem - mp * 80;
    signed char h = 0;
    if (kk < 64) {
        const int p  = mp >> 4, mo = mp & 15;
        const float wv = w[(size_t)(oblk*16 + mo) * I + ks*64 + kk];
        long long v = llrint((double)wv * 274877906944.0);   // w * 2^38, exact int
        int d = 0;
        for (int q = 0; q <= p; ++q) {                       // balanced base-256
            d = (int)((v + 128) & 255) - 128;
            v = (v - d) >> 8;
        }
        h = (signed char)d;
    }
    planes[f] = h;
}

// ====================== fused gemm+conv kernel ==============================
// grid (O/16, B). Per block: i8 digit-plane MFMA gemm over all 256 t ->
// exact fp64 a in LDS -> 61-tap FIR conv from LDS -> coalesced u stores.
template<int I>
__global__ __launch_bounds__(256)
void fused_gc(const uint32_t*    __restrict__ bitsT,   // [B][I/32][256]
              const signed char* __restrict__ planes,
              double*            __restrict__ u,       // [B][256][OS]
              int OS)
{
    constexpr int IW = I / 32;
    constexpr int NS = I / 64;
    __shared__ __align__(16) signed char ash[2][6400];   // 12.8 KB A dbuf
    __shared__ double a_lds[257 * 17];                   // 34.95 KB (row 256 = 0)
    __shared__ double srmE[68];

    const int tid  = threadIdx.x;
    const int lane = tid & 63;
    const int wvu  = tid >> 6;
    const int quad = lane >> 4;
    const int col  = lane & 15;
    const int b    = blockIdx.y;
    const int oblk = blockIdx.x;
    const int o0   = oblk * 16;
    const int tw   = wvu * 64;

    if (tid < 68) {
        const int k = tid - 2;
        double v = 0.0;
        if (k >= 1 && k <= 61) {
            double wv = (double)k / 8.0 * exp(1.0 - (double)k / 8.0);
            v = (double)(float)wv;     // fp32-rounded tap, widened (R1-R9)
        }
        srmE[tid] = v;
    }

    // ---------------- gemm: 5 i8 digit planes, K=64 (R9-verified) -----------
    const signed char* Apg = planes + (size_t)oblk * NS * 6400;
    const uint32_t*    bw  = bitsT + (size_t)b * IW * 256 + tw + col;

    v4i acc[5][4];
    #pragma unroll
    for (int p = 0; p < 5; ++p)
        #pragma unroll
        for (int nt = 0; nt < 4; ++nt)
            acc[p][nt] = (v4i){0, 0, 0, 0};

    uint4 st0, st1;
    auto ldglob = [&](int s) {                           // 400 uint4 per tile
        const uint4* src = (const uint4*)(Apg + (size_t)s * 6400);
        st0 = src[tid];
        if (tid < 144) st1 = src[256 + tid];
    };
    auto stw = [&](int s) {                              // linear, conflict-free
        uint4* dst = (uint4*)ash[s & 1];
        dst[tid] = st0;
        if (tid < 144) dst[256 + tid] = st1;
    };

    ldglob(0); stw(0);
    __syncthreads();

    for (int s = 0; s < NS; ++s) {
        const bool more = (s + 1 < NS);
        if (more) ldglob(s + 1);

        uint32_t m0[4], m1[4];
        #pragma unroll
        for (int nt = 0; nt < 4; ++nt) {
            m0[nt] = bw[(size_t)(2*s)     * 256 + nt * 16];
            m1[nt] = bw[(size_t)(2*s + 1) * 256 + nt * 16];
        }

        const signed char* ap = ash[s & 1];
        v4i af[5];
        #pragma unroll
        for (int p = 0; p < 5; ++p)
            af[p] = *(const v4i*)(const void*)(ap + (p*16 + col)*80 + quad*16);

        #pragma unroll
        for (int nt = 0; nt < 4; ++nt) {
            const uint32_t sel = (quad & 2) ? m1[nt] : m0[nt];
            const uint32_t h   = (sel >> ((quad & 1) * 16)) & 0xFFFFu;
            union { uint32_t uu[4]; v4i v; } bf;
            #pragma unroll
            for (int j = 0; j < 4; ++j) {
                const uint32_t n = (h >> (4*j)) & 0xFu;
                bf.uu[j] = (n * 0x00204081u) & 0x01010101u;  // 4 bits -> 4 i8 {0,1}
            }
            #pragma unroll
            for (int p = 0; p < 5; ++p)
                acc[p][nt] = __builtin_amdgcn_mfma_i32_16x16x64_i8(
                                 af[p], bf.v, acc[p][nt], 0, 0, 0);
        }

        if (more) stw(s + 1);
        __syncthreads();
    }

    // ---------------- recombine: exact fp64 a into LDS (R9-verified) --------
    const double inv = 1.0 / 274877906944.0;             // 2^-38
    #pragma unroll
    for (int nt = 0; nt < 4; ++nt) {
        const int t = tw + nt*16 + col;
        #pragma unroll
        for (int r = 0; r < 4; ++r) {
            double v =            (double)acc[4][nt][r];
            v = v * 256.0 + (double)acc[3][nt][r];
            v = v * 256.0 + (double)acc[2][nt][r];
            v = v * 256.0 + (double)acc[1][nt][r];
            v = v * 256.0 + (double)acc[0][nt][r];
            a_lds[t * 17 + quad*4 + r] = v * inv;
        }
    }
    if (tid < 17) a_lds[256 * 17 + tid] = 0.0;           // zero-guard row
    __syncthreads();

    // ---------------- conv: 61-tap FIR from LDS (R9-verified math) ----------
    const int o    = tid & 15;
    const int tgrp = tid >> 4;                           // 0..15
    #pragma unroll
    for (int pass = 0; pass < 4; ++pass) {
        const int T0b = pass * 64 + tgrp * 4;
        double u0 = 0, u1 = 0, u2 = 0, u3 = 0;
        double w1 = srmE[64], w2 = srmE[65], w3 = srmE[66];   // zero pads
        for (int d = 0; d < 64; d += 4) {
            const int row = T0b - 61 + d;
            const int r0 = (row + 0 < 0) ? 256 : row + 0;
            const int r1 = (row + 1 < 0) ? 256 : row + 1;
            const int r2 = (row + 2 < 0) ? 256 : row + 2;
            const int r3 = (row + 3 < 0) ? 256 : row + 3;
            const double av0 = a_lds[r0 * 17 + o];
            const double av1 = a_lds[r1 * 17 + o];
            const double av2 = a_lds[r2 * 17 + o];
            const double av3 = a_lds[r3 * 17 + o];
            const double n0 = srmE[63 - d], n1 = srmE[62 - d];
            const double n2 = srmE[61 - d], n3 = srmE[60 - d];
            u0 = fma(n0, av0, u0); u1 = fma(w1, av0, u1); u2 = fma(w2, av0, u2); u3 = fma(w3, av0, u3);
            u0 = fma(n1, av1, u0); u1 = fma(n0, av1, u1); u2 = fma(w1, av1, u2); u3 = fma(w2, av1, u3);
            u0 = fma(n2, av2, u0); u1 = fma(n1, av2, u1); u2 = fma(n0, av2, u2); u3 = fma(w1, av2, u3);
            u0 = fma(n3, av3, u0); u1 = fma(n2, av3, u1); u2 = fma(n1, av3, u2); u3 = fma(n0, av3, u3);
            w1 = n3; w2 = n2; w3 = n1;
        }
        double* up = u + ((size_t)b * 256 + T0b) * OS + o0 + o;
        up[0]              = u0;
        up[(size_t)OS]     = u1;
        up[(size_t)OS * 2] = u2;
        up[(size_t)OS * 3] = u3;
    }
}

// ========================== scan (R8-verified) ==============================
// lane = neuron; 256 sequential steps; refractory via 61-bit history mask.
// FINAL=false: ballots -> bitsT_out[b][word][t]. FINAL=true: f32 out[b][o][t].
template<bool FINAL>
__global__ __launch_bounds__(256)
void scan_spikes(const double* __restrict__ u, uint32_t* __restrict__ bitsT_out,
                 float* __restrict__ f32_out, int OS, int OW)
{
    __shared__ double   ref64[KLEN];
    __shared__ uint32_t blds[8][256];   // 8 KB ballot staging
    const int tid = threadIdx.x;
    if (tid < KLEN) {
        double v = (double)tid / 8.0 * exp(1.0 - (double)tid / 8.0);
        ref64[tid] = (double)(float)(-20.0 * v);
    }
    __syncthreads();

    const int b     = blockIdx.y;
    const int obase = blockIdx.x * 256;
    const int o     = obase + tid;
    const int lane  = tid & 63;
    const int wv    = tid >> 6;
    const double* up = u + (size_t)b * TT * OS + o;

    uint64_t mask = 0;
    double cur0 = up[0], cur1 = up[OS], cur2 = up[2 * (size_t)OS], cur3 = up[3 * (size_t)OS];
    for (int t0 = 0; t0 < TT; t0 += 4) {
        double nx0 = 0, nx1 = 0, nx2 = 0, nx3 = 0;
        if (t0 + 4 < TT) {
            const double* pp = up + (size_t)(t0 + 4) * OS;
            nx0 = pp[0]; nx1 = pp[OS]; nx2 = pp[2 * (size_t)OS]; nx3 = pp[3 * (size_t)OS];
        }
        #pragma unroll
        for (int q = 0; q < 4; ++q) {
            const double uv = (q == 0) ? cur0 : (q == 1) ? cur1 : (q == 2) ? cur2 : cur3;
            uint64_t m = mask;
            double r0 = 0.0, r1 = 0.0;
            while (m) {
                int p = __builtin_ctzll(m); m &= m - 1;
                r0 += ref64[p + 1];
                if (m) { int pq = __builtin_ctzll(m); m &= m - 1; r1 += ref64[pq + 1]; }
            }
            const bool s = (uv + (r0 + r1)) >= THETA;
            const uint64_t bal = __ballot(s);
            if (lane == 0) {
                blds[wv * 2 + 0][t0 + q] = (uint32_t)bal;
                blds[wv * 2 + 1][t0 + q] = (uint32_t)(bal >> 32);
            }
            mask = ((mask << 1) | (s ? 1ull : 0ull)) & ((1ull << 61) - 1ull);
        }
        cur0 = nx0; cur1 = nx1; cur2 = nx2; cur3 = nx3;
    }
    __syncthreads();

    if (!FINAL) {
        const int wordbase = obase >> 5;
        for (int e = tid; e < 8 * 256; e += 256) {
            const int wl = e >> 8, t = e & 255;
            bitsT_out[((size_t)b * OW + wordbase + wl) * TT + t] = blds[wl][t];
        }
    } else {
        // f32 epilogue: thread = t, loop over the block's 256 neurons
        for (int ol = 0; ol < 256; ++ol) {
            const uint32_t w = blds[ol >> 5][tid];
            f32_out[((size_t)b * 512 + obase + ol) * TT + tid] =
                (float)((w >> (ol & 31)) & 1u);
        }
    }
}

// ================================ launcher ==================================
extern "C" void kernel_launch(void* const* d_in, const int* in_sizes, int n_in,
                              void* d_out, int out_size, void* d_ws, size_t ws_size,
                              hipStream_t stream)
{
    const float* x  = (const float*)d_in[0];   // [32][1024][256]
    const float* w1 = (const float*)d_in[1];   // [2048][1024]
    const float* w2 = (const float*)d_in[2];   // [512][2048]
    float* out = (float*)d_out;                // [32][512][256]

    char* ws = (char*)d_ws;
    uint32_t* bits1 = (uint32_t*)ws;                        // 1 MB
    uint32_t* bitsH = (uint32_t*)(ws + (size_t)1048576);    // 2 MB
    size_t off = 1048576 + 2097152;
    signed char* P1 = (signed char*)(ws + off);             // 128*16*6400 = 13.1 MB
    off += (size_t)128 * 16 * 6400;
    signed char* P2 = (signed char*)(ws + off);             // 32*32*6400  = 6.55 MB
    off += (size_t)32 * 32 * 6400;
    off = (off + 255) & ~(size_t)255;
    double* uBuf = (double*)(ws + off);                     // 32*256*2048*8 = 134 MB

    bitifyT<<<dim3(32, 8), 256, 0, stream>>>(x, bits1);
    decompose_i8<<<dim3((13107200 + 255)/256), 256, 0, stream>>>(w1, P1, 1024, 13107200);
    decompose_i8<<<dim3((6553600  + 255)/256), 256, 0, stream>>>(w2, P2, 2048, 6553600);

    // layer 1: 1024 -> 2048
    fused_gc<1024><<<dim3(128, 32), 256, 0, stream>>>(bits1, P1, uBuf, 2048);
    scan_spikes<false><<<dim3(8, 32), 256, 0, stream>>>(uBuf, bitsH, nullptr, 2048, 64);
    // layer 2: 2048 -> 512
    fused_gc<2048><<<dim3(32, 32), 256, 0, stream>>>(bitsH, P2, uBuf, 512);
    scan_spikes<true><<<dim3(2, 32), 256, 0, stream>>>(uBuf, nullptr, out, 512, 16);
}